// Round 1
// baseline (811.326 us; speedup 1.0000x reference)
//
#include <hip/hip_runtime.h>

typedef unsigned short u16;
typedef unsigned int u32;
typedef __attribute__((ext_vector_type(8))) __bf16 bf16x8;
typedef __attribute__((ext_vector_type(4))) float f32x4;

#define CLEN 1664
#define SEQL 4992
#define NHEADS 16
#define HD 128
#define HID 2048
#define KVD 512
#define SCALE 0.08838834764831845f

__device__ __forceinline__ u16 f2bf(float f) {
  union { float f; u32 u; } v; v.f = f;
  u32 u = v.u;
  return (u16)((u + 0x7FFFu + ((u >> 16) & 1u)) >> 16);
}

__device__ __forceinline__ f32x4 mfma16(bf16x8 a, bf16x8 b, f32x4 c) {
  return __builtin_amdgcn_mfma_f32_16x16x32_bf16(a, b, c, 0, 0, 0);
}

// ---------------- f32 -> bf16 convert ----------------
__global__ void cvt_kernel(const float* __restrict__ src, u16* __restrict__ dst, int n) {
  int i = (blockIdx.x * blockDim.x + threadIdx.x) * 4;
  if (i >= n) return;
  float4 v = *(const float4*)(src + i);
  uint2 p;
  p.x = (u32)f2bf(v.x) | ((u32)f2bf(v.y) << 16);
  p.y = (u32)f2bf(v.z) | ((u32)f2bf(v.w) << 16);
  *(uint2*)(dst + i) = p;
}

// ---------------- RoPE (f32 src -> bf16 dst) ----------------
// mode 0: pid = s % CLEN ; mode 1: pid = s ; mode 2: pid = CLEN-1
__global__ void rope_kernel(const float* __restrict__ src, const float* __restrict__ cost,
                            const float* __restrict__ sint, u16* __restrict__ dst,
                            int nrows, int row0, int rowlen, int mode) {
  int idx = blockIdx.x * blockDim.x + threadIdx.x;
  if (idx >= nrows * rowlen) return;
  int r = idx / rowlen;
  int col = idx - r * rowlen;
  int s = row0 + r;
  int pid = (mode == 0) ? (s % CLEN) : (mode == 1 ? s : (CLEN - 1));
  int d = col & 127;
  float x = src[(size_t)s * rowlen + col];
  float xr = (d < 64) ? -src[(size_t)s * rowlen + col + 64]
                      :  src[(size_t)s * rowlen + col - 64];
  dst[(size_t)r * rowlen + col] = f2bf(x * cost[pid * 128 + d] + xr * sint[pid * 128 + d]);
}

// ---------------- GEMM: C[M][N] = A[M][K] * B[N][K]^T (bf16 in, f32 acc) ------
// EPI 0: f32 C ; EPI 1: bf16 C ; EPI 2: bf16 scatter C^T (vT layout [N][M])
template <int EPI>
__global__ __launch_bounds__(256) void gemm_bt(const u16* __restrict__ A, const u16* __restrict__ B,
                                               float* __restrict__ Cf, u16* __restrict__ Cb,
                                               int M, int N, int K) {
  __shared__ __align__(16) u16 Al[128 * 64];
  __shared__ __align__(16) u16 Bl[128 * 64];
  const int t = threadIdx.x;
  const int lane = t & 63, wid = t >> 6;
  const int g = lane >> 4, c = lane & 15;
  const int wr = wid >> 1, wc = wid & 1;
  const int m0 = blockIdx.x * 128, n0 = blockIdx.y * 128;

  f32x4 acc[4][4];
#pragma unroll
  for (int m = 0; m < 4; ++m)
#pragma unroll
    for (int n = 0; n < 4; ++n) acc[m][n] = (f32x4){0.f, 0.f, 0.f, 0.f};

  const int srow = t >> 3;        // 0..31
  const int scol = (t & 7) * 8;   // element col in [0,64)
  for (int k0 = 0; k0 < K; k0 += 64) {
    __syncthreads();
#pragma unroll
    for (int i = 0; i < 4; ++i) {
      const int r = i * 32 + srow;
      *(bf16x8*)(Al + r * 64 + scol) = *(const bf16x8*)(A + (size_t)(m0 + r) * K + k0 + scol);
      *(bf16x8*)(Bl + r * 64 + scol) = *(const bf16x8*)(B + (size_t)(n0 + r) * K + k0 + scol);
    }
    __syncthreads();
#pragma unroll
    for (int kk = 0; kk < 2; ++kk) {
      bf16x8 af[4], bfr[4];
#pragma unroll
      for (int m = 0; m < 4; ++m)
        af[m] = *(const bf16x8*)(Al + (wr * 64 + m * 16 + c) * 64 + kk * 32 + g * 8);
#pragma unroll
      for (int n = 0; n < 4; ++n)
        bfr[n] = *(const bf16x8*)(Bl + (wc * 64 + n * 16 + c) * 64 + kk * 32 + g * 8);
#pragma unroll
      for (int m = 0; m < 4; ++m)
#pragma unroll
        for (int n = 0; n < 4; ++n)
          acc[m][n] = mfma16(af[m], bfr[n], acc[m][n]);
    }
  }
#pragma unroll
  for (int m = 0; m < 4; ++m)
#pragma unroll
    for (int n = 0; n < 4; ++n)
#pragma unroll
      for (int j = 0; j < 4; ++j) {
        const int row = m0 + wr * 64 + m * 16 + 4 * g + j;
        const int col = n0 + wc * 64 + n * 16 + c;
        const float v = acc[m][n][j];
        if (EPI == 0) Cf[(size_t)row * N + col] = v;
        else if (EPI == 1) Cb[(size_t)row * N + col] = f2bf(v);
        else Cb[(size_t)col * M + row] = f2bf(v);
      }
}

// ---------------- fused chunk attention ----------------
// grid: (26 qtiles, 3 chunks, 16 heads), block 256 (4 waves x 16 q-rows)
__global__ __launch_bounds__(256) void attn_kernel(
    const u16* __restrict__ qa, const u16* __restrict__ qb, const u16* __restrict__ qf,
    const u16* __restrict__ kbf, const u16* __restrict__ vT, u16* __restrict__ aout) {
  __shared__ __align__(16) u16 Klds[32 * 128];   // [kv row][d], blocks XOR (row&7)
  __shared__ __align__(16) u16 Vlds[128 * 32];   // [d row][kv], blocks XOR ((row>>1)&3)
  __shared__ __align__(16) u16 Plds[4][16 * 32]; // per-wave [q][kv], blocks XOR ((row>>2)&3)

  const int qt = blockIdx.x, chunk = blockIdx.y, head = blockIdx.z;
  const int t = threadIdx.x, wid = t >> 6, lane = t & 63;
  const int g = lane >> 4, c = lane & 15;
  const int kvh = head >> 2;

  const int qcb = qt * 64 + wid * 16;   // wave q-row base within chunk
  const int qgb = chunk * CLEN + qcb;   // global q-row base

  float m_r[4], l_r[4];
  f32x4 oacc[8];
#pragma unroll
  for (int j = 0; j < 4; ++j) { m_r[j] = -1e30f; l_r[j] = 0.f; }
#pragma unroll
  for (int f = 0; f < 8; ++f) oacc[f] = (f32x4){0.f, 0.f, 0.f, 0.f};

  const int k_lrow = t >> 4, k_cb = t & 15;
  const int v_row = t >> 2, v_cb = t & 3;

  for (int seg = 0; seg <= chunk; ++seg) {
    const bool causal = (seg == chunk);
    const u16* qp; int qoff;
    if (seg == chunk)          { qp = qa; qoff = 0; }
    else if (seg == chunk - 1) { qp = qb; qoff = CLEN; }
    else                       { qp = qf; qoff = 2 * CLEN; }
    const int kvbase = seg * CLEN;

    bf16x8 aq[4];
    {
      const u16* qrow = qp + (size_t)(qgb + c - qoff) * HID + head * HD;
#pragma unroll
      for (int kk = 0; kk < 4; ++kk) aq[kk] = *(const bf16x8*)(qrow + kk * 32 + g * 8);
    }

    const int ntiles = causal ? (qt * 2 + 2) : (CLEN / 32);

    for (int kt = 0; kt < ntiles; ++kt) {
      const int kv0 = kt * 32;
      __syncthreads();
      // stage K tile [32][128]
#pragma unroll
      for (int i = 0; i < 2; ++i) {
        const int lr = i * 16 + k_lrow;
        bf16x8 val = *(const bf16x8*)(kbf + (size_t)(kvbase + kv0 + lr) * KVD + kvh * HD + k_cb * 8);
        *(bf16x8*)(Klds + lr * 128 + ((k_cb ^ (lr & 7)) * 8)) = val;
      }
      // stage V^T tile [128][32]
#pragma unroll
      for (int i = 0; i < 2; ++i) {
        const int vr = i * 64 + v_row;
        bf16x8 val = *(const bf16x8*)(vT + (size_t)(kvh * HD + vr) * SEQL + kvbase + kv0 + v_cb * 8);
        *(bf16x8*)(Vlds + vr * 32 + ((v_cb ^ ((vr >> 1) & 3)) * 8)) = val;
      }
      __syncthreads();

      const bool active = !causal || (kv0 <= qcb + 15);
      if (active) {
        f32x4 s0 = (f32x4){0.f, 0.f, 0.f, 0.f}, s1 = (f32x4){0.f, 0.f, 0.f, 0.f};
#pragma unroll
        for (int kk = 0; kk < 4; ++kk) {
          bf16x8 bk0 = *(const bf16x8*)(Klds + c * 128 + (((kk * 4 + g) ^ (c & 7)) * 8));
          bf16x8 bk1 = *(const bf16x8*)(Klds + (16 + c) * 128 + (((kk * 4 + g) ^ (c & 7)) * 8));
          s0 = mfma16(aq[kk], bk0, s0);
          s1 = mfma16(aq[kk], bk1, s1);
        }
        float sv0[4], sv1[4], mt[4];
#pragma unroll
        for (int j = 0; j < 4; ++j) {
          float v0 = s0[j] * SCALE;
          float v1 = s1[j] * SCALE;
          if (causal) {
            const int qpos = qcb + 4 * g + j;
            if (kv0 + c > qpos) v0 = -1e9f;
            if (kv0 + 16 + c > qpos) v1 = -1e9f;
          }
          sv0[j] = v0; sv1[j] = v1;
          mt[j] = fmaxf(v0, v1);
        }
#pragma unroll
        for (int msk = 1; msk <= 8; msk <<= 1)
#pragma unroll
          for (int j = 0; j < 4; ++j) mt[j] = fmaxf(mt[j], __shfl_xor(mt[j], msk));
        float al[4], rs[4], p0[4], p1[4];
#pragma unroll
        for (int j = 0; j < 4; ++j) {
          const float mn = fmaxf(m_r[j], mt[j]);
          al[j] = __expf(m_r[j] - mn);
          m_r[j] = mn;
          p0[j] = __expf(sv0[j] - mn);
          p1[j] = __expf(sv1[j] - mn);
          rs[j] = p0[j] + p1[j];
        }
#pragma unroll
        for (int msk = 1; msk <= 8; msk <<= 1)
#pragma unroll
          for (int j = 0; j < 4; ++j) rs[j] += __shfl_xor(rs[j], msk);
#pragma unroll
        for (int j = 0; j < 4; ++j) l_r[j] = l_r[j] * al[j] + rs[j];
        // write P (bf16) to per-wave LDS, swizzled
        u16* pl = &Plds[wid][0];
#pragma unroll
        for (int j = 0; j < 4; ++j) {
          const int row = 4 * g + j;
          pl[row * 32 + (((c >> 3) ^ g) * 8) + (c & 7)] = f2bf(p0[j]);
          pl[row * 32 + ((((c >> 3) + 2) ^ g) * 8) + (c & 7)] = f2bf(p1[j]);
        }
        // rescale O while the LDS writes drain
#pragma unroll
        for (int f = 0; f < 8; ++f)
#pragma unroll
          for (int j = 0; j < 4; ++j) oacc[f][j] *= al[j];
        asm volatile("s_waitcnt lgkmcnt(0)" ::: "memory");
        bf16x8 pa = *(const bf16x8*)(pl + c * 32 + ((g ^ ((c >> 2) & 3)) * 8));
#pragma unroll
        for (int f = 0; f < 8; ++f) {
          bf16x8 vb = *(const bf16x8*)(Vlds + (f * 16 + c) * 32 + ((g ^ ((c >> 1) & 3)) * 8));
          oacc[f] = mfma16(pa, vb, oacc[f]);
        }
      }
    }
  }
  // epilogue: normalize and store bf16 [4992][2048]
  float inv[4];
#pragma unroll
  for (int j = 0; j < 4; ++j) inv[j] = 1.0f / l_r[j];
#pragma unroll
  for (int f = 0; f < 8; ++f)
#pragma unroll
    for (int j = 0; j < 4; ++j) {
      const int grow = qgb + 4 * g + j;
      aout[(size_t)grow * HID + head * HD + f * 16 + c] = f2bf(oacc[f][j] * inv[j]);
    }
}

extern "C" void kernel_launch(void* const* d_in, const int* in_sizes, int n_in,
                              void* d_out, int out_size, void* d_ws, size_t ws_size,
                              hipStream_t stream) {
  (void)in_sizes; (void)n_in; (void)out_size; (void)ws_size;
  const float* hidden = (const float*)d_in[0];
  const float* q_cos = (const float*)d_in[2];
  const float* q_sin = (const float*)d_in[3];
  const float* qc_cos = (const float*)d_in[4];
  const float* qc_sin = (const float*)d_in[5];
  const float* k_cos = (const float*)d_in[6];
  const float* k_sin = (const float*)d_in[7];
  const float* Wq = (const float*)d_in[8];
  const float* Wk = (const float*)d_in[9];
  const float* Wv = (const float*)d_in[10];
  const float* Wo = (const float*)d_in[11];
  float* out = (float*)d_out;

  char* ws = (char*)d_ws;
  size_t off = 0;
  auto alloc = [&](size_t bytes) { char* p = ws + off; off += (bytes + 255) & ~(size_t)255; return p; };
  u16* h_bf  = (u16*)alloc((size_t)SEQL * HID * 2);
  u16* Wq_bf = (u16*)alloc((size_t)HID * HID * 2);
  u16* Wk_bf = (u16*)alloc((size_t)KVD * HID * 2);
  u16* Wv_bf = (u16*)alloc((size_t)KVD * HID * 2);
  u16* Wo_bf = (u16*)alloc((size_t)HID * HID * 2);
  float* q_tmp = (float*)alloc((size_t)SEQL * HID * 4);
  float* k_tmp = (float*)alloc((size_t)SEQL * KVD * 4);
  u16* qa   = (u16*)alloc((size_t)SEQL * HID * 2);
  u16* qb   = (u16*)alloc((size_t)2 * CLEN * HID * 2);
  u16* qf   = (u16*)alloc((size_t)CLEN * HID * 2);
  u16* k_bf = (u16*)alloc((size_t)SEQL * KVD * 2);
  u16* vT   = (u16*)alloc((size_t)KVD * SEQL * 2);
  u16* amrg = (u16*)q_tmp;  // alias: q_tmp is dead once rope kernels have run

  auto cvt = [&](const float* s, u16* d, int n) {
    cvt_kernel<<<dim3((n / 4 + 255) / 256), dim3(256), 0, stream>>>(s, d, n);
  };
  cvt(hidden, h_bf, SEQL * HID);
  cvt(Wq, Wq_bf, HID * HID);
  cvt(Wk, Wk_bf, KVD * HID);
  cvt(Wv, Wv_bf, KVD * HID);
  cvt(Wo, Wo_bf, HID * HID);

  gemm_bt<0><<<dim3(SEQL / 128, HID / 128), 256, 0, stream>>>(h_bf, Wq_bf, q_tmp, nullptr, SEQL, HID, HID);
  gemm_bt<0><<<dim3(SEQL / 128, KVD / 128), 256, 0, stream>>>(h_bf, Wk_bf, k_tmp, nullptr, SEQL, KVD, HID);
  gemm_bt<2><<<dim3(SEQL / 128, KVD / 128), 256, 0, stream>>>(h_bf, Wv_bf, nullptr, vT, SEQL, KVD, HID);

  auto rope = [&](const float* s, const float* ct, const float* st, u16* d,
                  int nrows, int row0, int rowlen, int mode) {
    int total = nrows * rowlen;
    rope_kernel<<<dim3((total + 255) / 256), dim3(256), 0, stream>>>(s, ct, st, d, nrows, row0, rowlen, mode);
  };
  rope(q_tmp, q_cos, q_sin, qa, SEQL, 0, HID, 0);
  rope(q_tmp, qc_cos, qc_sin, qb, 2 * CLEN, CLEN, HID, 0);
  rope(q_tmp, qc_cos, qc_sin, qf, CLEN, 2 * CLEN, HID, 2);
  rope(k_tmp, k_cos, k_sin, k_bf, SEQL, 0, KVD, 1);

  attn_kernel<<<dim3(CLEN / 64, 3, NHEADS), 256, 0, stream>>>(qa, qb, qf, k_bf, vT, amrg);

  gemm_bt<0><<<dim3(SEQL / 128, HID / 128), 256, 0, stream>>>(amrg, Wo_bf, out, nullptr, SEQL, HID, HID);
}